// Round 14
// baseline (243.471 us; speedup 1.0000x reference)
//
#include <hip/hip_runtime.h>
#include <math.h>

#define DM 512
#define NH 8
#define HD 64
#define BB 2
#define TT 2048
#define CHUNK 64
#define NC (TT / CHUNK)   /* 32 */
#define BH (BB * NH)      /* 16 */
#define ROWS (BB * TT)    /* 4096 */
#define EPSV 1e-6f
#define NBLK 512

typedef short bf16x8 __attribute__((ext_vector_type(8)));
typedef float f32x4 __attribute__((ext_vector_type(4)));
typedef unsigned short us;

union U4 { us h[4]; uint2 u; };

__device__ __forceinline__ us f2bf(float f) {
    unsigned int u = __float_as_uint(f);
    return (us)((u + 0x7FFFu + ((u >> 16) & 1u)) >> 16);
}
__device__ __forceinline__ float bf2f(us h) {
    return __uint_as_float(((unsigned int)h) << 16);
}
__device__ __forceinline__ void gload16(const void* g, void* l) {
    __builtin_amdgcn_global_load_lds(
        (const __attribute__((address_space(1))) unsigned int*)g,
        (__attribute__((address_space(3))) unsigned int*)l, 16, 0, 0);
}
#define SWZ(r, k) ((k) ^ (((r) & 7) << 3))
#define SWZT(row, col) ((((((col) >> 3) ^ ((row) & 15)) << 3)) | ((col) & 7))

// Manual grid barrier.  The poll MUST be SYSTEM scope: per-XCD L2s are not
// cross-coherent, and an agent-scope load is served from the local L2 whose
// copy of the counter line goes stale (R13: ~46us/barrier waiting for
// eviction).  System scope -> sc0+sc1 load -> bypasses L1+L2, reads the
// coherent point each poll with no cache invalidation (R12's bug).
__device__ __forceinline__ void gbar(unsigned* cnt, unsigned target) {
    __syncthreads();
    if (threadIdx.x == 0) {
        __hip_atomic_fetch_add(cnt, 1u, __ATOMIC_RELEASE, __HIP_MEMORY_SCOPE_SYSTEM);
        while (__hip_atomic_load(cnt, __ATOMIC_RELAXED, __HIP_MEMORY_SCOPE_SYSTEM) < target)
            __builtin_amdgcn_s_sleep(2);
        __builtin_amdgcn_fence(__ATOMIC_ACQUIRE, "agent");
    }
    __syncthreads();
}

// ---------------------------------------------------------------------------
// Phase bodies (bit-identical math to the R10-verified kernels).
// ---------------------------------------------------------------------------
__device__ __forceinline__ void prep_body(
    int bid, int tid, const float* __restrict__ x,
    const float* __restrict__ Wq, const float* __restrict__ Wk,
    const float* __restrict__ Wv, const float* __restrict__ Wo,
    us* __restrict__ xb, us* __restrict__ WT, us* sh)
{
    if (bid < 2048) {
        const int i = bid * 256 + tid;
        float4 v = ((const float4*)x)[i];
        U4 o;
        o.h[0] = f2bf(v.x); o.h[1] = f2bf(v.y);
        o.h[2] = f2bf(v.z); o.h[3] = f2bf(v.w);
        ((uint2*)xb)[i] = o.u;
    } else {
        float* tl = (float*)sh;              // [32][33]
        const int b2 = bid - 2048;
        const int which = b2 >> 8, t = b2 & 255;
        const float* W = (which == 0) ? Wq : (which == 1) ? Wk : (which == 2) ? Wv : Wo;
        us* O = WT + (size_t)which * DM * DM;
        const int r0 = (t >> 4) * 32, c0 = (t & 15) * 32;
        const int tr = tid >> 3, tc = tid & 7;
        float4 v = *(const float4*)&W[(size_t)(r0 + tr) * DM + c0 + tc * 4];
        tl[tr * 33 + tc * 4 + 0] = v.x; tl[tr * 33 + tc * 4 + 1] = v.y;
        tl[tr * 33 + tc * 4 + 2] = v.z; tl[tr * 33 + tc * 4 + 3] = v.w;
        __syncthreads();
        U4 o;
#pragma unroll
        for (int i = 0; i < 4; ++i) o.h[i] = f2bf(tl[(tc * 4 + i) * 33 + tr]);
        *(uint2*)&O[(size_t)(c0 + tr) * DM + r0 + tc * 4] = o.u;
    }
}

__device__ __forceinline__ void stage_tiles(
    const us* __restrict__ Ag, const us* __restrict__ Bg,
    int r0, int c0, int k0, int tid, us* As, us* Bs)
{
    const int fa = tid * 8;
#pragma unroll
    for (int i = 0; i < 2; ++i) {
        const int f = fa + i * 2048, row = f >> 6, kp = f & 63;
        gload16(Ag + (size_t)(r0 + row) * DM + k0 + SWZ(row, kp), As + f);
    }
#pragma unroll
    for (int i = 0; i < 4; ++i) {
        const int f = fa + i * 2048, row = f >> 6, kp = f & 63;
        gload16(Bg + (size_t)(c0 + row) * DM + k0 + SWZ(row, kp), Bs + f);
    }
}

__device__ __forceinline__ void gemm64x128(
    const us* __restrict__ Ag, const us* __restrict__ Bg,
    int r0, int c0, int tid, us* Asl, us* Bsl, f32x4 (&acc)[2][4])
{
    const int lane = tid & 63, wid = tid >> 6;
    const int wr = wid >> 1, wc = wid & 1;
    const int lrow = lane & 15, lk8 = (lane >> 4) * 8;

    stage_tiles(Ag, Bg, r0, c0, 0, tid, Asl, Bsl);
    __syncthreads();
    int cur = 0;
    for (int k0 = 0; k0 < DM; k0 += 64) {
        if (k0 + 64 < DM)
            stage_tiles(Ag, Bg, r0, c0, k0 + 64, tid,
                        Asl + (cur ^ 1) * 4096, Bsl + (cur ^ 1) * 8192);
        const us* As = Asl + cur * 4096;
        const us* Bs = Bsl + cur * 8192;
#pragma unroll
        for (int kin = 0; kin < 64; kin += 32) {
            bf16x8 af[2], bfr[4];
#pragma unroll
            for (int mi = 0; mi < 2; ++mi) {
                const int row = wr * 32 + mi * 16 + lrow;
                af[mi] = *(const bf16x8*)&As[row * 64 + SWZ(row, kin + lk8)];
            }
#pragma unroll
            for (int ni = 0; ni < 4; ++ni) {
                const int row = wc * 64 + ni * 16 + lrow;
                bfr[ni] = *(const bf16x8*)&Bs[row * 64 + SWZ(row, kin + lk8)];
            }
#pragma unroll
            for (int mi = 0; mi < 2; ++mi)
#pragma unroll
                for (int ni = 0; ni < 4; ++ni)
                    acc[mi][ni] = __builtin_amdgcn_mfma_f32_16x16x32_bf16(
                        af[mi], bfr[ni], acc[mi][ni], 0, 0, 0);
        }
        __syncthreads();
        cur ^= 1;
    }
}

__device__ __forceinline__ void qkv_body(
    int which, int r0, int c0, int tid,
    const us* __restrict__ xb, const us* __restrict__ WT,
    const float* __restrict__ bq, const float* __restrict__ bk,
    const float* __restrict__ bv,
    us* __restrict__ qn, us* __restrict__ kn,
    us* __restrict__ kt, us* __restrict__ vt, us* sh)
{
    const us* Bg = WT + (size_t)which * DM * DM;
    const float* bias = (which == 0) ? bq : (which == 1) ? bk : bv;
    us* Asl = sh;
    us* Bsl = sh + 8192;

    f32x4 acc[2][4] = {};
    gemm64x128(xb, Bg, r0, c0, tid, Asl, Bsl, acc);

    const int lane = tid & 63, wid = tid >> 6;
    const int wr = wid >> 1, wc = wid & 1;
    const int lrow = lane & 15, lr4 = (lane >> 4) * 4;
    const int b = r0 >> 11, t0b = r0 & (TT - 1);

    us* CbT = sh;
    us* CbD = sh + 8192;

#pragma unroll
    for (int mi = 0; mi < 2; ++mi) {
        const int tL = wr * 32 + mi * 16 + lr4;
#pragma unroll
        for (int ni = 0; ni < 4; ++ni) {
            const int colL = wc * 64 + ni * 16 + lrow;
            const float bc = bias[c0 + colL];
            U4 p4;
#pragma unroll
            for (int r = 0; r < 4; ++r) {
                float y = acc[mi][ni][r] + bc;
                if (which < 2) y = (y > 0.f) ? (y + 1.f) : __expf(y);
                p4.h[r] = f2bf(y);
            }
            if (which < 2) {
#pragma unroll
                for (int r = 0; r < 4; ++r)
                    CbT[(tL + r) * 128 + SWZT(tL + r, colL)] = p4.h[r];
            }
            if (which >= 1) *(uint2*)&CbD[colL * 72 + tL] = p4.u;
        }
    }
    __syncthreads();

    if (which < 2) {
        us* dstn = (which == 0) ? qn : kn;
#pragma unroll
        for (int it = 0; it < 4; ++it) {
            const int idx = it * 2048 + tid * 8;
            const int row = idx >> 7, col = idx & 127;
            const uint4 v = *(const uint4*)&CbT[row * 128 + SWZT(row, col)];
            const int h = (c0 + col) >> 6, d = col & 63;
            *(uint4*)&dstn[((size_t)(b * NH + h) * TT + t0b + row) * HD + d] = v;
        }
    }
    if (which >= 1) {
        us* dst = (which == 1) ? kt : vt;
        const int lane6 = tid & 63;
#pragma unroll
        for (int it = 0; it < 4; ++it) {
            const int colL = it * 32 + (tid >> 6) * 8 + (lane6 >> 3);
            const int tch = (lane6 & 7) * 8;
            const uint4 v = *(const uint4*)&CbD[colL * 72 + tch];
            const int col = c0 + colL, h = col >> 6, d = col & 63;
            *(uint4*)&dst[((size_t)(b * NH + h) * HD + d) * TT + t0b + tch] = v;
        }
    }
}

__device__ __forceinline__ void chunk_sums_body(
    int blk, int tid, const us* __restrict__ kt, const us* __restrict__ vt,
    us* __restrict__ kvc, float* __restrict__ zc, us* sh)
{
    const int bh = blk >> 5, c = blk & 31;
    const int t0 = c * CHUNK;
    us* Ksl = sh;
    us* Vsl = sh + 4096;
    float* partial = (float*)(sh + 16384);       // [4][64]
    const us* ktb = kt + (size_t)bh * HD * TT;
    const us* vtb = vt + (size_t)bh * HD * TT;

#pragma unroll
    for (int i = 0; i < 2; ++i) {
        const int f = tid * 8 + i * 2048, row = f >> 6, kp = f & 63;
        const int kl = SWZ(row, kp);
        gload16(ktb + (size_t)row * TT + t0 + kl, Ksl + f);
        gload16(vtb + (size_t)row * TT + t0 + kl, Vsl + f);
    }
    __syncthreads();

    const int lane = tid & 63, wid = tid >> 6;
    const int wr = wid >> 1, wc = wid & 1;
    const int lrow = lane & 15, lk8 = (lane >> 4) * 8, lr4 = (lane >> 4) * 4;

    f32x4 acc[2][2] = {};
#pragma unroll
    for (int kin = 0; kin < 64; kin += 32) {
        bf16x8 af[2], bfr[2];
#pragma unroll
        for (int mi = 0; mi < 2; ++mi) {
            const int row = wr * 32 + mi * 16 + lrow;
            af[mi] = *(const bf16x8*)&Vsl[row * 64 + SWZ(row, kin + lk8)];
        }
#pragma unroll
        for (int ni = 0; ni < 2; ++ni) {
            const int row = wc * 32 + ni * 16 + lrow;
            bfr[ni] = *(const bf16x8*)&Ksl[row * 64 + SWZ(row, kin + lk8)];
        }
#pragma unroll
        for (int mi = 0; mi < 2; ++mi)
#pragma unroll
            for (int ni = 0; ni < 2; ++ni)
                acc[mi][ni] = __builtin_amdgcn_mfma_f32_16x16x32_bf16(
                    af[mi], bfr[ni], acc[mi][ni], 0, 0, 0);
    }

    us* dst = kvc + (size_t)blk * 4096;
#pragma unroll
    for (int mi = 0; mi < 2; ++mi)
#pragma unroll
        for (int ni = 0; ni < 2; ++ni) {
            const int d2 = wr * 32 + mi * 16 + lr4;
            const int d1 = wc * 32 + ni * 16 + lrow;
#pragma unroll
            for (int r = 0; r < 4; ++r)
                dst[(d2 + r) * 64 + d1] = f2bf(acc[mi][ni][r]);
        }

    {
        const int p = tid >> 6, d = tid & 63;
        float s = 0.f;
#pragma unroll
        for (int j = 0; j < 16; ++j)
            s += bf2f(Ksl[d * 64 + SWZ(d, p * 16 + j)]);
        partial[p * 64 + d] = s;
    }
    __syncthreads();
    if (tid < 64)
        zc[(size_t)blk * 64 + tid] = partial[0 * 64 + tid] + partial[1 * 64 + tid] +
                                     partial[2 * 64 + tid] + partial[3 * 64 + tid];
}

__device__ __forceinline__ void scan_body(
    int bh, int seg, int tid, const us* __restrict__ kvc,
    const float* __restrict__ zc, us* __restrict__ spr, float* __restrict__ zpr)
{
    if (seg < 8) {
        const int e = seg * 512 + tid * 2;
        const size_t base = (size_t)(bh * NC) * 4096 + e;
        unsigned u[NC];
#pragma unroll
        for (int c = 0; c < NC; ++c)
            u[c] = *(const unsigned*)(kvc + base + (size_t)c * 4096);
        float r0 = 0.f, r1 = 0.f;
#pragma unroll
        for (int c = 0; c < NC; ++c) {
            const unsigned p = (unsigned)f2bf(r0) | ((unsigned)f2bf(r1) << 16);
            *(unsigned*)(spr + base + (size_t)c * 4096) = p;
            r0 += bf2f((us)(u[c] & 0xFFFF));
            r1 += bf2f((us)(u[c] >> 16));
        }
    } else if (tid < 64) {
        const size_t base = (size_t)(bh * NC) * 64 + tid;
        float zv[NC];
#pragma unroll
        for (int c = 0; c < NC; ++c) zv[c] = zc[base + (size_t)c * 64];
        float run = 0.f;
#pragma unroll
        for (int c = 0; c < NC; ++c) {
            zpr[base + (size_t)c * 64] = run;
            run += zv[c];
        }
    }
}

__device__ __forceinline__ void chunk_attn_body(
    int blk, int tid, const us* __restrict__ qn, const us* __restrict__ kn,
    const us* __restrict__ vt, const us* __restrict__ spr,
    const float* __restrict__ zpr, us* __restrict__ attn, us* sh)
{
    const int bh = blk >> 5, c = blk & 31;
    const int t0 = c * CHUNK;
    us* Qs  = sh;
    us* Kns = sh + 4096;
    us* Vts = sh + 8192;
    us* Sts = sh + 12288;
    us* Abf = sh + 16384;
    float* zp   = (float*)(sh + 20480);
    float* den  = (float*)(sh + 20608);
    float* part = (float*)(sh + 20736);

    const us* qb = qn + ((size_t)bh * TT + t0) * HD;
    const us* kb = kn + ((size_t)bh * TT + t0) * HD;
    const us* vb = vt + (size_t)bh * HD * TT;
    const us* sb = spr + (size_t)blk * 4096;

#pragma unroll
    for (int i = 0; i < 2; ++i) {
        const int f = tid * 8 + i * 2048, row = f >> 6, kp = f & 63;
        const int kl = SWZ(row, kp);
        gload16(qb + (size_t)row * HD + kl, Qs + f);
        gload16(kb + (size_t)row * HD + kl, Kns + f);
        gload16(vb + (size_t)row * TT + t0 + kl, Vts + f);
        gload16(sb + (size_t)row * 64 + kl, Sts + f);
    }
    if (tid < 64) zp[tid] = zpr[(size_t)blk * 64 + tid];
    __syncthreads();

    const int lane = tid & 63, wid = tid >> 6;
    const int wr = wid >> 1, wc = wid & 1;
    const int lrow = lane & 15, lk8 = (lane >> 4) * 8, lr4 = (lane >> 4) * 4;

    f32x4 accs[2][2] = {};
#pragma unroll
    for (int kin = 0; kin < 64; kin += 32) {
        bf16x8 af[2], bfr[2];
#pragma unroll
        for (int mi = 0; mi < 2; ++mi) {
            const int row = wr * 32 + mi * 16 + lrow;
            af[mi] = *(const bf16x8*)&Qs[row * 64 + SWZ(row, kin + lk8)];
        }
#pragma unroll
        for (int ni = 0; ni < 2; ++ni) {
            const int row = wc * 32 + ni * 16 + lrow;
            bfr[ni] = *(const bf16x8*)&Kns[row * 64 + SWZ(row, kin + lk8)];
        }
#pragma unroll
        for (int mi = 0; mi < 2; ++mi)
#pragma unroll
            for (int ni = 0; ni < 2; ++ni)
                accs[mi][ni] = __builtin_amdgcn_mfma_f32_16x16x32_bf16(
                    af[mi], bfr[ni], accs[mi][ni], 0, 0, 0);
    }

#pragma unroll
    for (int mi = 0; mi < 2; ++mi)
#pragma unroll
        for (int ni = 0; ni < 2; ++ni) {
            const int j = wc * 32 + ni * 16 + lrow;
#pragma unroll
            for (int r = 0; r < 4; ++r) {
                const int i = wr * 32 + mi * 16 + lr4 + r;
                const float v = (j <= i) ? accs[mi][ni][r] : 0.f;
                Abf[i * 64 + SWZ(i, j)] = f2bf(v);
            }
        }
    __syncthreads();

    {
        const int p = tid >> 6, i = tid & 63;
        float s = 0.f;
#pragma unroll
        for (int jj = 0; jj < 16; ++jj) {
            const int j = p * 16 + jj;
            s += bf2f(Abf[i * 64 + SWZ(i, j)]);
            s += bf2f(Qs[i * 64 + SWZ(i, j)]) * zp[j];
        }
        part[p * 64 + i] = s;
    }
    __syncthreads();
    if (tid < 64)
        den[tid] = fmaxf(part[0 * 64 + tid] + part[1 * 64 + tid] +
                         part[2 * 64 + tid] + part[3 * 64 + tid], EPSV);
    __syncthreads();

    f32x4 acco[2][2] = {};
#pragma unroll
    for (int kin = 0; kin < 64; kin += 32) {
        bf16x8 af[2], bfr[2], ag[2], bgr[2];
#pragma unroll
        for (int mi = 0; mi < 2; ++mi) {
            const int row = wr * 32 + mi * 16 + lrow;
            af[mi] = *(const bf16x8*)&Abf[row * 64 + SWZ(row, kin + lk8)];
            ag[mi] = *(const bf16x8*)&Qs[row * 64 + SWZ(row, kin + lk8)];
        }
#pragma unroll
        for (int ni = 0; ni < 2; ++ni) {
            const int row = wc * 32 + ni * 16 + lrow;
            bfr[ni] = *(const bf16x8*)&Vts[row * 64 + SWZ(row, kin + lk8)];
            bgr[ni] = *(const bf16x8*)&Sts[row * 64 + SWZ(row, kin + lk8)];
        }
#pragma unroll
        for (int mi = 0; mi < 2; ++mi)
#pragma unroll
            for (int ni = 0; ni < 2; ++ni) {
                acco[mi][ni] = __builtin_amdgcn_mfma_f32_16x16x32_bf16(
                    af[mi], bfr[ni], acco[mi][ni], 0, 0, 0);
                acco[mi][ni] = __builtin_amdgcn_mfma_f32_16x16x32_bf16(
                    ag[mi], bgr[ni], acco[mi][ni], 0, 0, 0);
            }
    }

    const int b = bh >> 3, h = bh & 7;
#pragma unroll
    for (int mi = 0; mi < 2; ++mi)
#pragma unroll
        for (int ni = 0; ni < 2; ++ni) {
            const int d2 = wc * 32 + ni * 16 + lrow;
#pragma unroll
            for (int r = 0; r < 4; ++r) {
                const int i = wr * 32 + mi * 16 + lr4 + r;
                attn[((size_t)b * TT + t0 + i) * DM + h * HD + d2] =
                    f2bf(acco[mi][ni][r] / den[i]);
            }
        }
}

__device__ __forceinline__ void out_body(
    int r0, int c0, int tid, const us* __restrict__ Ag,
    const us* __restrict__ WoT, const float* __restrict__ bias,
    float* __restrict__ out, us* sh)
{
    us* Asl = sh;
    us* Bsl = sh + 8192;
    f32x4 acc[2][4] = {};
    gemm64x128(Ag, WoT, r0, c0, tid, Asl, Bsl, acc);

    const int lane = tid & 63, wid = tid >> 6;
    const int wr = wid >> 1, wc = wid & 1;
    const int lrow = lane & 15, lr4 = (lane >> 4) * 4;

#pragma unroll
    for (int mi = 0; mi < 2; ++mi)
#pragma unroll
        for (int ni = 0; ni < 4; ++ni) {
            const int col = c0 + wc * 64 + ni * 16 + lrow;
            const float bc = bias[col];
#pragma unroll
            for (int r = 0; r < 4; ++r) {
                const int row = r0 + wr * 32 + mi * 16 + lr4 + r;
                out[(size_t)row * DM + col] = acc[mi][ni][r] + bc;
            }
        }
}

// ---------------------------------------------------------------------------
// Megakernel with manual grid barriers (plain launch -> graph-capture-safe).
// 512 blocks x 256 threads; 48 KB LDS + launch_bounds(256,2) => co-resident.
// ---------------------------------------------------------------------------
__global__ __launch_bounds__(256, 2) void mega(
    const float* __restrict__ x,
    const float* __restrict__ Wq, const float* __restrict__ bq,
    const float* __restrict__ Wk, const float* __restrict__ bk,
    const float* __restrict__ Wv, const float* __restrict__ bv,
    const float* __restrict__ Wo, const float* __restrict__ bo,
    float* __restrict__ out,
    us* __restrict__ xb, us* __restrict__ WT,
    us* __restrict__ qn, us* __restrict__ kn,
    us* __restrict__ kt, us* __restrict__ vt,
    us* __restrict__ kvc, us* __restrict__ spr,
    float* __restrict__ zc, float* __restrict__ zpr,
    us* __restrict__ attn, unsigned* __restrict__ bar)
{
    __shared__ alignas(16) us sh[24576];        // 48 KB arena, aliased per phase
    const int blk = blockIdx.x, tid = threadIdx.x;

    // P0: prep (3072 logical blocks, 6 per block)
    for (int vb = blk; vb < 3072; vb += NBLK) {
        prep_body(vb, tid, x, Wq, Wk, Wv, Wo, xb, WT, sh);
        __syncthreads();
    }
    gbar(bar, 1 * NBLK);

    // P1: qkv (768 logical)
    for (int lb = blk; lb < 768; lb += NBLK) {
        const int which = lb >> 8, rc = lb & 255;
        qkv_body(which, (rc >> 2) * 64, (rc & 3) * 128, tid,
                 xb, WT, bq, bk, bv, qn, kn, kt, vt, sh);
        __syncthreads();
    }
    gbar(bar, 2 * NBLK);

    // P2: chunk_sums (512 logical)
    chunk_sums_body(blk, tid, kt, vt, kvc, zc, sh);
    gbar(bar, 3 * NBLK);

    // P3: scan (144 logical)
    if (blk < 144) scan_body(blk & 15, blk >> 4, tid, kvc, zc, spr, zpr);
    gbar(bar, 4 * NBLK);

    // P4: chunk_attn (512 logical)
    chunk_attn_body(blk, tid, qn, kn, vt, spr, zpr, attn, sh);
    gbar(bar, 5 * NBLK);

    // P5: out projection (256 logical)
    if (blk < 256)
        out_body((blk >> 2) * 64, (blk & 3) * 128, tid,
                 attn, WT + (size_t)3 * DM * DM, bo, out, sh);
}

// ---------------------------------------------------------------------------
extern "C" void kernel_launch(void* const* d_in, const int* in_sizes, int n_in,
                              void* d_out, int out_size, void* d_ws, size_t ws_size,
                              hipStream_t stream)
{
    const float* x  = (const float*)d_in[0];
    const float* Wq = (const float*)d_in[1];
    const float* bq = (const float*)d_in[2];
    const float* Wk = (const float*)d_in[3];
    const float* bk = (const float*)d_in[4];
    const float* Wv = (const float*)d_in[5];
    const float* bv = (const float*)d_in[6];
    const float* Wo = (const float*)d_in[7];
    const float* bo = (const float*)d_in[8];
    float* out = (float*)d_out;

    const size_t SZ = (size_t)BH * TT * HD;        // 2,097,152 elems
    us* xb  = (us*)d_ws;                            // aliased as attn later
    us* WT  = xb + SZ;
    us* qn  = WT + (size_t)4 * DM * DM;
    us* kn  = qn + SZ;
    us* kt  = kn + SZ;
    us* vt  = kt + SZ;
    us* kvc = vt + SZ;
    us* spr = kvc + SZ;
    float* zc  = (float*)(spr + SZ);
    float* zpr = zc + (size_t)BH * NC * 64;
    unsigned* bar = (unsigned*)(zpr + (size_t)BH * NC * 64);
    us* attn = xb;

    hipMemsetAsync(bar, 0, sizeof(unsigned), stream);
    mega<<<NBLK, 256, 0, stream>>>(
        x, Wq, bq, Wk, bk, Wv, bv, Wo, bo, out,
        xb, WT, qn, kn, kt, vt, kvc, spr, zc, zpr, attn, bar);
}

// Round 15
// 45.799 us; speedup vs baseline: 5.3160x; 5.3160x over previous
//
#include <hip/hip_runtime.h>
#include <math.h>

#define DM 512
#define NH 8
#define HD 64
#define BB 2
#define TT 2048
#define CHUNK 64
#define NC (TT / CHUNK)   /* 32 */
#define BH (BB * NH)      /* 16 */
#define ROWS (BB * TT)    /* 4096 */
#define EPSV 1e-6f

typedef short bf16x8 __attribute__((ext_vector_type(8)));
typedef float f32x4 __attribute__((ext_vector_type(4)));
typedef unsigned short us;

union U4 { us h[4]; uint2 u; };

__device__ __forceinline__ us f2bf(float f) {
    unsigned int u = __float_as_uint(f);
    return (us)((u + 0x7FFFu + ((u >> 16) & 1u)) >> 16);
}
__device__ __forceinline__ float bf2f(us h) {
    return __uint_as_float(((unsigned int)h) << 16);
}
__device__ __forceinline__ void gload16(const void* g, void* l) {
    __builtin_amdgcn_global_load_lds(
        (const __attribute__((address_space(1))) unsigned int*)g,
        (__attribute__((address_space(3))) unsigned int*)l, 16, 0, 0);
}
// XOR swizzle on 16B blocks within a 64-elem bf16 row.
#define SWZ(r, k) ((k) ^ (((r) & 7) << 3))
// chunk-XOR swizzle for the t-major C bounce (128-elem rows, 16B blocks)
#define SWZT(row, col) ((((((col) >> 3) ^ ((row) & 15)) << 3)) | ((col) & 7))

// ---------------------------------------------------------------------------
// prep: blocks [0,2048): x f32 -> xb bf16.  blocks [2048,3072): W -> W^T bf16.
// ---------------------------------------------------------------------------
__global__ __launch_bounds__(256) void prep(
    const float* __restrict__ x,
    const float* __restrict__ Wq, const float* __restrict__ Wk,
    const float* __restrict__ Wv, const float* __restrict__ Wo,
    us* __restrict__ xb, us* __restrict__ WT)
{
    const int bid = blockIdx.x, tid = threadIdx.x;
    __shared__ float tl[32][33];
    if (bid < 2048) {
        const int i = bid * 256 + tid;
        float4 v = ((const float4*)x)[i];
        U4 o;
        o.h[0] = f2bf(v.x); o.h[1] = f2bf(v.y);
        o.h[2] = f2bf(v.z); o.h[3] = f2bf(v.w);
        ((uint2*)xb)[i] = o.u;
    } else {
        const int b2 = bid - 2048;
        const int which = b2 >> 8, t = b2 & 255;
        const float* W = (which == 0) ? Wq : (which == 1) ? Wk : (which == 2) ? Wv : Wo;
        us* O = WT + (size_t)which * DM * DM;
        const int r0 = (t >> 4) * 32, c0 = (t & 15) * 32;
        const int tr = tid >> 3, tc = tid & 7;
        float4 v = *(const float4*)&W[(size_t)(r0 + tr) * DM + c0 + tc * 4];
        tl[tr][tc * 4 + 0] = v.x; tl[tr][tc * 4 + 1] = v.y;
        tl[tr][tc * 4 + 2] = v.z; tl[tr][tc * 4 + 3] = v.w;
        __syncthreads();
        U4 o;
#pragma unroll
        for (int i = 0; i < 4; ++i) o.h[i] = f2bf(tl[tc * 4 + i][tr]);
        *(uint2*)&O[(size_t)(c0 + tr) * DM + r0 + tc * 4] = o.u;
    }
}

// ---------------------------------------------------------------------------
// Double-buffered 64x128 GEMM core (bf16): C = A[64xDM] @ B[128xDM]^T.
// T3-min: STAGE(next) issued before compute, ONE barrier per K-step.
// ---------------------------------------------------------------------------
__device__ __forceinline__ void stage_tiles(
    const us* __restrict__ Ag, const us* __restrict__ Bg,
    int r0, int c0, int k0, int tid, us* As, us* Bs)
{
    const int fa = tid * 8;
#pragma unroll
    for (int i = 0; i < 2; ++i) {
        const int f = fa + i * 2048, row = f >> 6, kp = f & 63;
        gload16(Ag + (size_t)(r0 + row) * DM + k0 + SWZ(row, kp), As + f);
    }
#pragma unroll
    for (int i = 0; i < 4; ++i) {
        const int f = fa + i * 2048, row = f >> 6, kp = f & 63;
        gload16(Bg + (size_t)(c0 + row) * DM + k0 + SWZ(row, kp), Bs + f);
    }
}

__device__ __forceinline__ void gemm64x128(
    const us* __restrict__ Ag, const us* __restrict__ Bg,
    int r0, int c0, int tid, us* Asl, us* Bsl, f32x4 (&acc)[2][4])
{
    const int lane = tid & 63, wid = tid >> 6;
    const int wr = wid >> 1, wc = wid & 1;
    const int lrow = lane & 15, lk8 = (lane >> 4) * 8;

    stage_tiles(Ag, Bg, r0, c0, 0, tid, Asl, Bsl);
    __syncthreads();
    int cur = 0;
    for (int k0 = 0; k0 < DM; k0 += 64) {
        if (k0 + 64 < DM)
            stage_tiles(Ag, Bg, r0, c0, k0 + 64, tid,
                        Asl + (cur ^ 1) * 4096, Bsl + (cur ^ 1) * 8192);
        const us* As = Asl + cur * 4096;
        const us* Bs = Bsl + cur * 8192;
#pragma unroll
        for (int kin = 0; kin < 64; kin += 32) {
            bf16x8 af[2], bfr[4];
#pragma unroll
            for (int mi = 0; mi < 2; ++mi) {
                const int row = wr * 32 + mi * 16 + lrow;
                af[mi] = *(const bf16x8*)&As[row * 64 + SWZ(row, kin + lk8)];
            }
#pragma unroll
            for (int ni = 0; ni < 4; ++ni) {
                const int row = wc * 64 + ni * 16 + lrow;
                bfr[ni] = *(const bf16x8*)&Bs[row * 64 + SWZ(row, kin + lk8)];
            }
#pragma unroll
            for (int mi = 0; mi < 2; ++mi)
#pragma unroll
                for (int ni = 0; ni < 4; ++ni)
                    acc[mi][ni] = __builtin_amdgcn_mfma_f32_16x16x32_bf16(
                        af[mi], bfr[ni], acc[mi][ni], 0, 0, 0);
        }
        __syncthreads();
        cur ^= 1;
    }
}

// ---------------------------------------------------------------------------
// QKV projection.  ALL outputs go through LDS bounces (reusing the staging
// LDS after the GEMM's final barrier) for fully coalesced global stores.
// ---------------------------------------------------------------------------
__global__ __launch_bounds__(256) void qkv_mfma(
    const us* __restrict__ xb, const us* __restrict__ WT,
    const float* __restrict__ bq, const float* __restrict__ bk,
    const float* __restrict__ bv,
    us* __restrict__ qn, us* __restrict__ kn,
    us* __restrict__ kt, us* __restrict__ vt)
{
    const int which = blockIdx.z;
    const us* Bg = WT + (size_t)which * DM * DM;
    const float* bias = (which == 0) ? bq : (which == 1) ? bk : bv;

    __shared__ us sh[24576];           // dbuf staging (48KB); reused as Cb
    us* Asl = sh;
    us* Bsl = sh + 8192;

    f32x4 acc[2][4] = {};
    const int r0 = blockIdx.x * 64, c0 = blockIdx.y * 128;
    const int tid = threadIdx.x;

    gemm64x128(xb, Bg, r0, c0, tid, Asl, Bsl, acc);

    const int lane = tid & 63, wid = tid >> 6;
    const int wr = wid >> 1, wc = wid & 1;
    const int lrow = lane & 15, lr4 = (lane >> 4) * 4;
    const int b = r0 >> 11, t0b = r0 & (TT - 1);

    us* CbT = sh;                      // [64][128] t-major (swizzled), 16 KB
    us* CbD = sh + 8192;               // [128][72] d-major t-runs, 18 KB

#pragma unroll
    for (int mi = 0; mi < 2; ++mi) {
        const int tL = wr * 32 + mi * 16 + lr4;
#pragma unroll
        for (int ni = 0; ni < 4; ++ni) {
            const int colL = wc * 64 + ni * 16 + lrow;
            const float bc = bias[c0 + colL];
            U4 p4;
#pragma unroll
            for (int r = 0; r < 4; ++r) {
                float y = acc[mi][ni][r] + bc;
                if (which < 2) y = (y > 0.f) ? (y + 1.f) : __expf(y);
                p4.h[r] = f2bf(y);
            }
            if (which < 2) {
#pragma unroll
                for (int r = 0; r < 4; ++r)
                    CbT[(tL + r) * 128 + SWZT(tL + r, colL)] = p4.h[r];
            }
            if (which >= 1) *(uint2*)&CbD[colL * 72 + tL] = p4.u;
        }
    }
    __syncthreads();

    if (which < 2) {                   // qn or kn: natural [bh][t][d]
        us* dstn = (which == 0) ? qn : kn;
#pragma unroll
        for (int it = 0; it < 4; ++it) {
            const int idx = it * 2048 + tid * 8;
            const int row = idx >> 7, col = idx & 127;
            const uint4 v = *(const uint4*)&CbT[row * 128 + SWZT(row, col)];
            const int h = (c0 + col) >> 6, d = col & 63;
            *(uint4*)&dstn[((size_t)(b * NH + h) * TT + t0b + row) * HD + d] = v;
        }
    }
    if (which >= 1) {                  // kt or vt: transposed [bh][d][t]
        us* dst = (which == 1) ? kt : vt;
#pragma unroll
        for (int it = 0; it < 4; ++it) {
            const int colL = it * 32 + wid * 8 + (lane >> 3);
            const int tch = (lane & 7) * 8;
            const uint4 v = *(const uint4*)&CbD[colL * 72 + tch];
            const int col = c0 + colL, h = col >> 6, d = col & 63;
            *(uint4*)&dst[((size_t)(b * NH + h) * HD + d) * TT + t0b + tch] = v;
        }
    }
}

// ---------------------------------------------------------------------------
// Output projection: out = attn(bf16) @ Wo^T + bo, f32 out.
// ---------------------------------------------------------------------------
__global__ __launch_bounds__(256) void out_mfma(
    const us* __restrict__ Ag, const us* __restrict__ WoT,
    const float* __restrict__ bias, float* __restrict__ out)
{
    __shared__ us Asl[2 * 4096];
    __shared__ us Bsl[2 * 8192];
    f32x4 acc[2][4] = {};
    const int r0 = blockIdx.x * 64, c0 = blockIdx.y * 128;
    const int tid = threadIdx.x;

    gemm64x128(Ag, WoT, r0, c0, tid, Asl, Bsl, acc);

    const int lane = tid & 63, wid = tid >> 6;
    const int wr = wid >> 1, wc = wid & 1;
    const int lrow = lane & 15, lr4 = (lane >> 4) * 4;

#pragma unroll
    for (int mi = 0; mi < 2; ++mi)
#pragma unroll
        for (int ni = 0; ni < 4; ++ni) {
            const int col = c0 + wc * 64 + ni * 16 + lrow;
            const float bc = bias[col];
#pragma unroll
            for (int r = 0; r < 4; ++r) {
                const int row = r0 + wr * 32 + mi * 16 + lr4 + r;
                out[(size_t)row * DM + col] = acc[mi][ni][r] + bc;
            }
        }
}

// ---------------------------------------------------------------------------
// chunk_sums: LDS-staged, coalesced.  S^T_c[d2][d1] (bf16) and z_c (f32).
// ---------------------------------------------------------------------------
__global__ __launch_bounds__(256) void chunk_sums(
    const us* __restrict__ kt, const us* __restrict__ vt,
    us* __restrict__ kvc, float* __restrict__ zc)
{
    const int blk = blockIdx.x, bh = blk >> 5, c = blk & 31;
    const int t0 = c * CHUNK;
    __shared__ us Ksl[4096], Vsl[4096];
    __shared__ float partial[4][64];
    const int tid = threadIdx.x;
    const us* ktb = kt + (size_t)bh * HD * TT;
    const us* vtb = vt + (size_t)bh * HD * TT;

#pragma unroll
    for (int i = 0; i < 2; ++i) {
        const int f = tid * 8 + i * 2048, row = f >> 6, kp = f & 63;
        const int kl = SWZ(row, kp);
        gload16(ktb + (size_t)row * TT + t0 + kl, Ksl + f);
        gload16(vtb + (size_t)row * TT + t0 + kl, Vsl + f);
    }
    __syncthreads();

    const int lane = tid & 63, wid = tid >> 6;
    const int wr = wid >> 1, wc = wid & 1;
    const int lrow = lane & 15, lk8 = (lane >> 4) * 8, lr4 = (lane >> 4) * 4;

    f32x4 acc[2][2] = {};
#pragma unroll
    for (int kin = 0; kin < 64; kin += 32) {
        bf16x8 af[2], bfr[2];
#pragma unroll
        for (int mi = 0; mi < 2; ++mi) {
            const int row = wr * 32 + mi * 16 + lrow;
            af[mi] = *(const bf16x8*)&Vsl[row * 64 + SWZ(row, kin + lk8)];
        }
#pragma unroll
        for (int ni = 0; ni < 2; ++ni) {
            const int row = wc * 32 + ni * 16 + lrow;
            bfr[ni] = *(const bf16x8*)&Ksl[row * 64 + SWZ(row, kin + lk8)];
        }
#pragma unroll
        for (int mi = 0; mi < 2; ++mi)
#pragma unroll
            for (int ni = 0; ni < 2; ++ni)
                acc[mi][ni] = __builtin_amdgcn_mfma_f32_16x16x32_bf16(
                    af[mi], bfr[ni], acc[mi][ni], 0, 0, 0);
    }

    us* dst = kvc + (size_t)blk * 4096;
#pragma unroll
    for (int mi = 0; mi < 2; ++mi)
#pragma unroll
        for (int ni = 0; ni < 2; ++ni) {
            const int d2 = wr * 32 + mi * 16 + lr4;
            const int d1 = wc * 32 + ni * 16 + lrow;
#pragma unroll
            for (int r = 0; r < 4; ++r)
                dst[(d2 + r) * 64 + d1] = f2bf(acc[mi][ni][r]);
        }

    // z: row sums of K^T (logical [d][t])
    {
        const int p = tid >> 6, d = tid & 63;
        float s = 0.f;
#pragma unroll
        for (int j = 0; j < 16; ++j)
            s += bf2f(Ksl[d * 64 + SWZ(d, p * 16 + j)]);
        partial[p][d] = s;
    }
    __syncthreads();
    if (tid < 64)
        zc[(size_t)blk * 64 + tid] =
            partial[0][tid] + partial[1][tid] + partial[2][tid] + partial[3][tid];
}

// ---------------------------------------------------------------------------
// scan: exclusive prefix over chunks, register-blocked two-phase.
// ---------------------------------------------------------------------------
__global__ __launch_bounds__(256) void scan(
    const us* __restrict__ kvc, const float* __restrict__ zc,
    us* __restrict__ spr, float* __restrict__ zpr)
{
    const int bh = blockIdx.x, seg = blockIdx.y, tid = threadIdx.x;
    if (seg < 8) {
        const int e = seg * 512 + tid * 2;
        const size_t base = (size_t)(bh * NC) * 4096 + e;
        unsigned u[NC];
#pragma unroll
        for (int c = 0; c < NC; ++c)
            u[c] = *(const unsigned*)(kvc + base + (size_t)c * 4096);
        float r0 = 0.f, r1 = 0.f;
#pragma unroll
        for (int c = 0; c < NC; ++c) {
            const unsigned p = (unsigned)f2bf(r0) | ((unsigned)f2bf(r1) << 16);
            *(unsigned*)(spr + base + (size_t)c * 4096) = p;
            r0 += bf2f((us)(u[c] & 0xFFFF));
            r1 += bf2f((us)(u[c] >> 16));
        }
    } else if (tid < 64) {
        const size_t base = (size_t)(bh * NC) * 64 + tid;
        float zv[NC];
#pragma unroll
        for (int c = 0; c < NC; ++c) zv[c] = zc[base + (size_t)c * 64];
        float run = 0.f;
#pragma unroll
        for (int c = 0; c < NC; ++c) {
            zpr[base + (size_t)c * 64] = run;
            run += zv[c];
        }
    }
}

// ---------------------------------------------------------------------------
// chunk_attn: LDS-staged QK^T -> mask -> FUSED num/den MFMA pass.
// den = rowsum(A) + Q.z via virtual ones/z B-columns (R6/R7-verified) +
// 16-lane shfl broadcast.  Only 2 block barriers total (was 4).
// ---------------------------------------------------------------------------
__global__ __launch_bounds__(256) void chunk_attn(
    const us* __restrict__ qn, const us* __restrict__ kn,
    const us* __restrict__ vt, const us* __restrict__ spr,
    const float* __restrict__ zpr, us* __restrict__ attn)
{
    const int blk = blockIdx.x, bh = blk >> 5, c = blk & 31;
    const int t0 = c * CHUNK;
    __shared__ us Qs[4096], Kns[4096], Vts[4096], Sts[4096], Abf[4096];
    __shared__ float zp[64];
    const int tid = threadIdx.x;

    const us* qb = qn + ((size_t)bh * TT + t0) * HD;
    const us* kb = kn + ((size_t)bh * TT + t0) * HD;
    const us* vb = vt + (size_t)bh * HD * TT;
    const us* sb = spr + (size_t)blk * 4096;

#pragma unroll
    for (int i = 0; i < 2; ++i) {
        const int f = tid * 8 + i * 2048, row = f >> 6, kp = f & 63;
        const int kl = SWZ(row, kp);
        gload16(qb + (size_t)row * HD + kl, Qs + f);
        gload16(kb + (size_t)row * HD + kl, Kns + f);
        gload16(vb + (size_t)row * TT + t0 + kl, Vts + f);
        gload16(sb + (size_t)row * 64 + kl, Sts + f);
    }
    if (tid < 64) zp[tid] = zpr[(size_t)blk * 64 + tid];
    __syncthreads();

    const int lane = tid & 63, wid = tid >> 6;
    const int wr = wid >> 1, wc = wid & 1;
    const int lrow = lane & 15, lk8 = (lane >> 4) * 8, lr4 = (lane >> 4) * 4;

    // QK^T
    f32x4 accs[2][2] = {};
#pragma unroll
    for (int kin = 0; kin < 64; kin += 32) {
        bf16x8 af[2], bfr[2];
#pragma unroll
        for (int mi = 0; mi < 2; ++mi) {
            const int row = wr * 32 + mi * 16 + lrow;
            af[mi] = *(const bf16x8*)&Qs[row * 64 + SWZ(row, kin + lk8)];
        }
#pragma unroll
        for (int ni = 0; ni < 2; ++ni) {
            const int row = wc * 32 + ni * 16 + lrow;
            bfr[ni] = *(const bf16x8*)&Kns[row * 64 + SWZ(row, kin + lk8)];
        }
#pragma unroll
        for (int mi = 0; mi < 2; ++mi)
#pragma unroll
            for (int ni = 0; ni < 2; ++ni)
                accs[mi][ni] = __builtin_amdgcn_mfma_f32_16x16x32_bf16(
                    af[mi], bfr[ni], accs[mi][ni], 0, 0, 0);
    }

    // mask + bf16 store of scores
#pragma unroll
    for (int mi = 0; mi < 2; ++mi)
#pragma unroll
        for (int ni = 0; ni < 2; ++ni) {
            const int j = wc * 32 + ni * 16 + lrow;
#pragma unroll
            for (int r = 0; r < 4; ++r) {
                const int i = wr * 32 + mi * 16 + lr4 + r;
                const float v = (j <= i) ? accs[mi][ni][r] : 0.f;
                Abf[i * 64 + SWZ(i, j)] = f2bf(v);
            }
        }
    __syncthreads();

    // virtual B columns for den (col 0 = ones / z, other cols zero)
    bf16x8 onesB = {}, zB = {};
    if (lrow == 0) {
#pragma unroll
        for (int e = 0; e < 8; ++e) {
            onesB[e] = (short)0x3F80;
            zB[e] = (short)f2bf(zp[lk8 + e]);
        }
    }

    // num = A@V + Q@S ; den = A@ones + Q@z  (fused)
    f32x4 acco[2][2] = {};
    f32x4 accd[2] = {};
#pragma unroll
    for (int kin = 0; kin < 64; kin += 32) {
        bf16x8 af_a[2], af_q[2], bfr[2], bgr[2];
#pragma unroll
        for (int mi = 0; mi < 2; ++mi) {
            const int row = wr * 32 + mi * 16 + lrow;
            af_a[mi] = *(const bf16x8*)&Abf[row * 64 + SWZ(row, kin + lk8)];
            af_q[mi] = *(const bf16x8*)&Qs[row * 64 + SWZ(row, kin + lk8)];
        }
#pragma unroll
        for (int ni = 0; ni < 2; ++ni) {
            const int row = wc * 32 + ni * 16 + lrow;
            bfr[ni] = *(const bf16x8*)&Vts[row * 64 + SWZ(row, kin + lk8)];
            bgr[ni] = *(const bf16x8*)&Sts[row * 64 + SWZ(row, kin + lk8)];
        }
#pragma unroll
        for (int mi = 0; mi < 2; ++mi) {
            accd[mi] = __builtin_amdgcn_mfma_f32_16x16x32_bf16(
                af_a[mi], onesB, accd[mi], 0, 0, 0);
            accd[mi] = __builtin_amdgcn_mfma_f32_16x16x32_bf16(
                af_q[mi], zB, accd[mi], 0, 0, 0);
#pragma unroll
            for (int ni = 0; ni < 2; ++ni) {
                acco[mi][ni] = __builtin_amdgcn_mfma_f32_16x16x32_bf16(
                    af_a[mi], bfr[ni], acco[mi][ni], 0, 0, 0);
                acco[mi][ni] = __builtin_amdgcn_mfma_f32_16x16x32_bf16(
                    af_q[mi], bgr[ni], acco[mi][ni], 0, 0, 0);
            }
        }
    }

    // den sits in col-0 lanes (lrow==0); broadcast within 16-lane groups
    float denr[2][4];
#pragma unroll
    for (int mi = 0; mi < 2; ++mi)
#pragma unroll
        for (int r = 0; r < 4; ++r)
            denr[mi][r] = fmaxf(__shfl(accd[mi][r], (int)(lane & 48), 64), EPSV);

    const int b = bh >> 3, h = bh & 7;
#pragma unroll
    for (int mi = 0; mi < 2; ++mi)
#pragma unroll
        for (int ni = 0; ni < 2; ++ni) {
            const int d2 = wc * 32 + ni * 16 + lrow;
#pragma unroll
            for (int r = 0; r < 4; ++r) {
                const int i = wr * 32 + mi * 16 + lr4 + r;
                attn[((size_t)b * TT + t0 + i) * DM + h * HD + d2] =
                    f2bf(acco[mi][ni][r] / denr[mi][r]);
            }
        }
}

// ---------------------------------------------------------------------------
extern "C" void kernel_launch(void* const* d_in, const int* in_sizes, int n_in,
                              void* d_out, int out_size, void* d_ws, size_t ws_size,
                              hipStream_t stream)
{
    const float* x  = (const float*)d_in[0];
    const float* Wq = (const float*)d_in[1];
    const float* bq = (const float*)d_in[2];
    const float* Wk = (const float*)d_in[3];
    const float* bk = (const float*)d_in[4];
    const float* Wv = (const float*)d_in[5];
    const float* bv = (const float*)d_in[6];
    const float* Wo = (const float*)d_in[7];
    const float* bo = (const float*)d_in[8];
    float* out = (float*)d_out;

    const size_t SZ = (size_t)BH * TT * HD;        // 2,097,152 elems
    us* xb  = (us*)d_ws;                            // aliased as attn later
    us* WT  = xb + SZ;
    us* qn  = WT + (size_t)4 * DM * DM;
    us* kn  = qn + SZ;
    us* kt  = kn + SZ;
    us* vt  = kt + SZ;
    us* kvc = vt + SZ;
    us* spr = kvc + SZ;
    float* zc  = (float*)(spr + SZ);
    float* zpr = zc + (size_t)BH * NC * 64;
    us* attn = xb;

    prep<<<3072, 256, 0, stream>>>(x, Wq, Wk, Wv, Wo, xb, WT);
    qkv_mfma<<<dim3(ROWS / 64, DM / 128, 3), 256, 0, stream>>>(
        xb, WT, bq, bk, bv, qn, kn, kt, vt);
    chunk_sums<<<BH * NC, 256, 0, stream>>>(kt, vt, kvc, zc);
    scan<<<dim3(BH, 9), 256, 0, stream>>>(kvc, zc, spr, zpr);
    chunk_attn<<<BH * NC, 256, 0, stream>>>(qn, kn, vt, spr, zpr, attn);
    out_mfma<<<dim3(ROWS / 64, DM / 128), 256, 0, stream>>>(
        attn, WT + (size_t)3 * DM * DM, bo, out);
}